// Round 1
// baseline (440.633 us; speedup 1.0000x reference)
//
#include <hip/hip_runtime.h>

#define IMG_H 1024
#define IMG_W 1024
#define NBATCH 8
#define NCH 3
#define NPIX (IMG_H * IMG_W)
#define SEGS 64                         // 16-row bands per image
#define ROWS_PER_SEG 16
#define NTOT (8388608LL)                // 8 * 1024 * 1024

#define BINS1 4096                      // level-1: bits >> 19
#define SH1 19

// ---- workspace layout (bytes) ----
#define WS_MISC_OFF   0                 // zeroed: lossAcc @0 (8B), gCnt[16] @64, sel1 @128, resid1 @256
#define WS_MISC_BYTES 4096
#define WS_H1P_OFF    (WS_MISC_OFF + WS_MISC_BYTES)
#define WS_H1P_BYTES  (2 * NBATCH * SEGS * BINS1 * 2)  // 8 MB
#define WS_LIST_OFF   (WS_H1P_OFF + WS_H1P_BYTES)

struct Row3f { float l, c, r; };
struct Row4  { float l, c0, c1, r; };   // two adjacent pixels + halo

// BIT-EXACT vs reference: f32, row-major sequential tap order (verified earlier session).
__device__ __forceinline__ float sobel_g(const Row3f& r0, const Row3f& r1, const Row3f& r2) {
    float gx = r0.r - r0.l;
    gx -= 2.0f * r1.l;
    gx += 2.0f * r1.r;
    gx -= r2.l;
    gx += r2.r;
    float gy = r0.l + 2.0f * r0.c;
    gy += r0.r;
    gy -= r2.l;
    gy -= 2.0f * r2.c;
    gy -= r2.r;
    return fabsf(gx) + fabsf(gy);
}

// Load 2 adjacent pixels (columns c0, c0+1) + left/right halo for row y.
// Halo comes from neighbor lanes via shuffle; wave-edge lanes do a scalar load.
// y is wave-uniform, so the OOB early-out is non-divergent.
__device__ __forceinline__ Row4 load_row2(const float* __restrict__ img, int y, int c0, int lane) {
    Row4 o;
    if ((unsigned)y >= (unsigned)IMG_H) { o.l = o.c0 = o.c1 = o.r = 0.0f; return o; }
    const float* row = img + (size_t)y * IMG_W;
    const float2 v = *reinterpret_cast<const float2*>(row + c0);
    float lf = __shfl_up(v.y, 1);
    float rt = __shfl_down(v.x, 1);
    if (lane == 0)  lf = (c0 > 0) ? row[c0 - 1] : 0.0f;
    if (lane == 63) rt = (c0 + 2 < IMG_W) ? row[c0 + 2] : 0.0f;
    o.l = lf; o.c0 = v.x; o.c1 = v.y; o.r = rt;
    return o;
}

__device__ __forceinline__ void sobel2(const Row4& r0, const Row4& r1, const Row4& r2,
                                       float& g0, float& g1) {
    g0 = sobel_g(Row3f{r0.l,  r0.c0, r0.c1}, Row3f{r1.l,  r1.c0, r1.c1}, Row3f{r2.l,  r2.c0, r2.c1});
    g1 = sobel_g(Row3f{r0.c0, r0.c1, r0.r }, Row3f{r1.c0, r1.c1, r1.r }, Row3f{r2.c0, r2.c1, r2.r });
}

__device__ __forceinline__ unsigned wave_scan(unsigned s, int lane) {
    #pragma unroll
    for (int off = 1; off < 64; off <<= 1) {
        const unsigned v = __shfl_up(s, off);
        if (lane >= off) s += v;
    }
    return s;
}

// ---------------- pass 0: loss + level-1 histograms (2 replicated LDS copies) ----------------
extern "C" __global__ __launch_bounds__(512)
void k_pass0(const float* __restrict__ A, const float* __restrict__ B,
             const float* __restrict__ F,
             unsigned short* __restrict__ hist1p, double* __restrict__ lossAcc)
{
    __shared__ unsigned int h[4 * BINS1];   // 64 KB: copy0[A|B], copy1[A|B]
    __shared__ double lsum[8];
    const int t = threadIdx.x;
    const int lane = t & 63;
    for (int i = t; i < 4 * BINS1; i += 512) h[i] = 0u;
    __syncthreads();

    const int blk = blockIdx.x;             // 512 = 8 batches * 64 segs
    const int batch = blk >> 6;
    const int seg = blk & 63;
    const int y0 = seg * ROWS_PER_SEG;
    const int c0 = 2 * t;                   // this thread's two columns
    unsigned int* hc = h + (t >> 8) * (2 * BINS1);   // half-block replicated copy

    const float* a = A + (size_t)batch * NCH * NPIX;
    const float* b = B + (size_t)batch * NCH * NPIX;
    const float* f = F + (size_t)batch * NCH * NPIX;

    Row4 a0 = load_row2(a, y0 - 1, c0, lane), a1 = load_row2(a, y0, c0, lane), a2;
    Row4 b0 = load_row2(b, y0 - 1, c0, lane), b1 = load_row2(b, y0, c0, lane), b2;
    Row4 f0 = load_row2(f, y0 - 1, c0, lane), f1 = load_row2(f, y0, c0, lane), f2;

    double loss = 0.0;
    for (int i = 0; i < ROWS_PER_SEG; ++i) {
        const int y = y0 + i;
        a2 = load_row2(a, y + 1, c0, lane);
        b2 = load_row2(b, y + 1, c0, lane);
        f2 = load_row2(f, y + 1, c0, lane);
        float gA0, gA1, gB0, gB1, gF0, gF1;
        sobel2(a0, a1, a2, gA0, gA1);
        sobel2(b0, b1, b2, gB0, gB1);
        sobel2(f0, f1, f2, gF0, gF1);

        const unsigned bA0 = __float_as_uint(gA0) >> SH1, bA1 = __float_as_uint(gA1) >> SH1;
        atomicAdd(&hc[bA0], (bA0 == bA1) ? 2u : 1u);
        if (bA0 != bA1) atomicAdd(&hc[bA1], 1u);
        const unsigned bB0 = __float_as_uint(gB0) >> SH1, bB1 = __float_as_uint(gB1) >> SH1;
        atomicAdd(&hc[BINS1 + bB0], (bB0 == bB1) ? 2u : 1u);
        if (bB0 != bB1) atomicAdd(&hc[BINS1 + bB1], 1u);

        loss += (double)fabsf(gF0 - fmaxf(gA0, gB0));
        loss += (double)fabsf(gF1 - fmaxf(gA1, gB1));
        a0 = a1; a1 = a2;
        b0 = b1; b1 = b2;
        f0 = f1; f1 = f2;
    }
    __syncthreads();

    unsigned short* oA = hist1p + ((size_t)batch            * SEGS + seg) * BINS1;
    unsigned short* oB = hist1p + ((size_t)(NBATCH + batch) * SEGS + seg) * BINS1;
    for (int i = t; i < 2 * BINS1; i += 512) {          // sum copies; counts <= 16384 -> u16
        const unsigned v = h[i] + h[2 * BINS1 + i];
        if (i < BINS1) oA[i] = (unsigned short)v;
        else           oB[i - BINS1] = (unsigned short)v;
    }

    for (int off = 32; off > 0; off >>= 1) loss += __shfl_down(loss, off);
    if (lane == 0) lsum[t >> 6] = loss;
    __syncthreads();
    if (t == 0) {
        double s = 0.0;
        for (int i = 0; i < 8; ++i) s += lsum[i];
        atomicAdd(lossAcc, s);
    }
}

// ---------------- select1: reduce per-seg hists + rank-select level-1 bin (merged) ----------------
extern "C" __global__ __launch_bounds__(1024)
void k_select1(const unsigned short* __restrict__ hist1p, const int* __restrict__ kptr,
               int* __restrict__ sel1, int* __restrict__ resid1)
{
    const int ib = blockIdx.x, t = threadIdx.x;     // 16 blocks: [A batches | B batches]
    const int lane = t & 63, wid = t >> 6;

    long long kl = (long long)kptr[0];
    if (kl < 1 || kl > (long long)NPIX) {           // defensive: scalar sent as f32?
        float kf = ((const float*)kptr)[0];
        kl = (long long)kf;
        if (kl < 1) kl = 1;
        if (kl > NPIX) kl = NPIX;
    }
    const unsigned k = (unsigned)kl;

    // reduce 64 segs for bins 4t..4t+3 (coalesced ushort4 per lane)
    const ushort4* p = reinterpret_cast<const ushort4*>(hist1p + (size_t)ib * SEGS * BINS1) + t;
    unsigned c0 = 0, c1 = 0, c2 = 0, c3 = 0;
    #pragma unroll 4
    for (int sg = 0; sg < SEGS; ++sg) {
        const ushort4 v = p[(size_t)sg * (BINS1 / 4)];
        c0 += v.x; c1 += v.y; c2 += v.z; c3 += v.w;
    }
    const unsigned s = c0 + c1 + c2 + c3;

    // block inclusive scan: wave shfl-scan + cross-wave (2 barriers)
    unsigned incl = wave_scan(s, lane);
    __shared__ unsigned wsum[16];
    if (lane == 63) wsum[wid] = incl;
    __syncthreads();
    if (wid == 0) {
        unsigned w = (lane < 16) ? wsum[lane] : 0u;
        w = wave_scan(w, lane);
        if (lane < 16) wsum[lane] = w;
    }
    __syncthreads();
    if (wid > 0) incl += wsum[wid - 1];

    const unsigned excl = incl - s;
    if (excl < k && k <= incl) {                    // unique winner thread
        unsigned cum = excl; int bin = t * 4;
        if (cum + c0 < k) { cum += c0; ++bin;
          if (cum + c1 < k) { cum += c1; ++bin;
            if (cum + c2 < k) { cum += c2; ++bin; } } }
        sel1[ib] = bin;
        resid1[ib] = (int)(k - cum);
    }
}

// ---------------- pass B: masks + boundary-pixel candidate lists (barrier-free) ----------------
#define PB_BUF   256
#define PB_FLUSH 128

__device__ __forceinline__ void wave_flush(const uint2* __restrict__ wbuf, unsigned n,
                                           unsigned int* __restrict__ gcnt,
                                           uint2* __restrict__ dst, unsigned cap, int lane)
{
    __builtin_amdgcn_wave_barrier();                // order LDS writes before cross-lane reads
    unsigned base = 0;
    if (lane == 0) base = atomicAdd(gcnt, n);
    base = __shfl(base, 0);
    for (unsigned j = (unsigned)lane; j < n; j += 64u) {
        const unsigned d = base + j;
        if (d < cap) dst[d] = wbuf[j];
    }
}

extern "C" __global__ __launch_bounds__(512)
void k_passB(const float* __restrict__ A, const float* __restrict__ B,
             const int* __restrict__ sel1, unsigned int* __restrict__ gCnt,
             uint2* __restrict__ list, unsigned cap, float* __restrict__ out)
{
    const int t = threadIdx.x;
    const int lane = t & 63, wid = t >> 6;          // 8 waves
    const int blk = blockIdx.x;                     // 512 = 8 batches * 64 bands
    const int batch = blk >> 6;
    const int y0 = (blk & 63) * ROWS_PER_SEG;
    const int c0 = 2 * t;

    const float* a = A + (size_t)batch * NCH * NPIX;
    const float* b = B + (size_t)batch * NCH * NPIX;
    const unsigned sA = (unsigned)sel1[batch];
    const unsigned sB = (unsigned)sel1[NBATCH + batch];
    float* mA = out + 1 + (size_t)batch * NPIX;
    float* mB = out + 1 + (size_t)NTOT + (size_t)batch * NPIX;
    unsigned int* cA = &gCnt[batch];
    unsigned int* cB = &gCnt[NBATCH + batch];
    uint2* LA = list + (size_t)batch * cap;
    uint2* LB = list + (size_t)(NBATCH + batch) * cap;

    __shared__ uint2 buf[8][2][PB_BUF];             // 32 KB per-wave staging
    uint2 (*bufA)[PB_BUF] = &buf[wid][0];
    uint2 (*bufB)[PB_BUF] = &buf[wid][1];
    unsigned wcA = 0, wcB = 0;                      // wave-uniform register counters

    Row4 a0 = load_row2(a, y0 - 1, c0, lane), a1 = load_row2(a, y0, c0, lane), a2;
    Row4 b0 = load_row2(b, y0 - 1, c0, lane), b1 = load_row2(b, y0, c0, lane), b2;

    for (int i = 0; i < ROWS_PER_SEG; ++i) {
        const int y = y0 + i;
        a2 = load_row2(a, y + 1, c0, lane);
        b2 = load_row2(b, y + 1, c0, lane);
        float gA0, gA1, gB0, gB1;
        sobel2(a0, a1, a2, gA0, gA1);
        sobel2(b0, b1, b2, gB0, gB1);
        const unsigned uA0 = __float_as_uint(gA0), uA1 = __float_as_uint(gA1);
        const unsigned uB0 = __float_as_uint(gB0), uB1 = __float_as_uint(gB1);
        const unsigned bA0 = uA0 >> SH1, bA1 = uA1 >> SH1;
        const unsigned bB0 = uB0 >> SH1, bB1 = uB1 >> SH1;
        const unsigned idx = (unsigned)y * IMG_W + (unsigned)c0;

        *reinterpret_cast<float2*>(mA + idx) =
            make_float2((bA0 > sA) ? 1.0f : 0.0f, (bA1 > sA) ? 1.0f : 0.0f);
        *reinterpret_cast<float2*>(mB + idx) =
            make_float2((bB0 > sB) ? 1.0f : 0.0f, (bB1 > sB) ? 1.0f : 0.0f);

        const unsigned long long lt = ((unsigned long long)1 << lane) - 1ull;
        {   // A candidates: ballot-aggregated wave append, no barriers
            const unsigned long long m0 = __ballot(bA0 == sA);
            const unsigned long long m1 = __ballot(bA1 == sA);
            const unsigned n0 = (unsigned)__popcll(m0);
            const unsigned n01 = n0 + (unsigned)__popcll(m1);
            if (n01) {
                if (bA0 == sA) (*bufA)[wcA + (unsigned)__popcll(m0 & lt)] = make_uint2(uA0, idx);
                if (bA1 == sA) (*bufA)[wcA + n0 + (unsigned)__popcll(m1 & lt)] = make_uint2(uA1, idx + 1);
                wcA += n01;                          // wcA <= 127+128 < PB_BUF
                if (wcA >= PB_FLUSH) { wave_flush(*bufA, wcA, cA, LA, cap, lane); wcA = 0; }
            }
        }
        {   // B candidates
            const unsigned long long m0 = __ballot(bB0 == sB);
            const unsigned long long m1 = __ballot(bB1 == sB);
            const unsigned n0 = (unsigned)__popcll(m0);
            const unsigned n01 = n0 + (unsigned)__popcll(m1);
            if (n01) {
                if (bB0 == sB) (*bufB)[wcB + (unsigned)__popcll(m0 & lt)] = make_uint2(uB0, idx);
                if (bB1 == sB) (*bufB)[wcB + n0 + (unsigned)__popcll(m1 & lt)] = make_uint2(uB1, idx + 1);
                wcB += n01;
                if (wcB >= PB_FLUSH) { wave_flush(*bufB, wcB, cB, LB, cap, lane); wcB = 0; }
            }
        }
        a0 = a1; a1 = a2;
        b0 = b1; b1 = b2;
    }
    if (wcA) wave_flush(*bufA, wcA, cA, LA, cap, lane);
    if (wcB) wave_flush(*bufB, wcB, cB, LB, cap, lane);
}

// ---------------- selectfix: 19-bit select within boundary bin + mask fix-up ----------------
extern "C" __global__ __launch_bounds__(1024)
void k_selectfix(const uint2* __restrict__ list, const unsigned int* __restrict__ gCnt,
                 unsigned cap, const int* __restrict__ sel1, const int* __restrict__ resid1,
                 const double* __restrict__ lossAcc, float* __restrict__ out)
{
    const int ib = blockIdx.x, t = threadIdx.x;     // 16 blocks: [A batches | B batches]
    const int lane = t & 63, wid = t >> 6;
    unsigned n = gCnt[ib]; if (n > cap) n = cap;
    const unsigned kk = (unsigned)resid1[ib];
    const uint2* L = list + (size_t)ib * cap;

    __shared__ unsigned h2[BINS1];                  // 16 KB, reused for h3
    __shared__ unsigned wsum[16];
    __shared__ unsigned bcast[4];
    if (t < 4) bcast[t] = 0u;
    for (int i = t; i < BINS1; i += 1024) h2[i] = 0u;
    __syncthreads();

    // level-2: hist of (bits>>7)&4095 (all entries share bits>>19 == sel1)
    for (unsigned j = t; j < n; j += 1024u) atomicAdd(&h2[(L[j].x >> 7) & 4095u], 1u);
    __syncthreads();

    const unsigned c0 = h2[4 * t], c1 = h2[4 * t + 1], c2 = h2[4 * t + 2], c3 = h2[4 * t + 3];
    const unsigned s = c0 + c1 + c2 + c3;
    unsigned incl = wave_scan(s, lane);
    if (lane == 63) wsum[wid] = incl;
    __syncthreads();
    if (wid == 0) {
        unsigned w = (lane < 16) ? wsum[lane] : 0u;
        w = wave_scan(w, lane);
        if (lane < 16) wsum[lane] = w;
    }
    __syncthreads();
    if (wid > 0) incl += wsum[wid - 1];
    {
        const unsigned excl = incl - s;
        if (excl < kk && kk <= incl) {
            unsigned cum = excl; unsigned bin = 4u * t;
            if (cum + c0 < kk) { cum += c0; ++bin;
              if (cum + c1 < kk) { cum += c1; ++bin;
                if (cum + c2 < kk) { cum += c2; ++bin; } } }
            bcast[0] = bin;
            bcast[1] = kk - cum;
        }
    }
    __syncthreads();
    const unsigned sel2 = bcast[0], k3 = bcast[1];

    // level-3: hist of bits&127 among entries matching sel2
    if (t < 128) h2[t] = 0u;
    __syncthreads();
    for (unsigned j = t; j < n; j += 1024u) {
        const unsigned bbits = L[j].x;
        if (((bbits >> 7) & 4095u) == sel2) atomicAdd(&h2[bbits & 127u], 1u);
    }
    __syncthreads();
    {
        const unsigned s3 = (t < 128) ? h2[t] : 0u;
        unsigned incl3 = wave_scan(s3, lane);
        if (lane == 63) wsum[wid] = incl3;
        __syncthreads();
        if (wid == 0) {
            unsigned w = (lane < 16) ? wsum[lane] : 0u;
            w = wave_scan(w, lane);
            if (lane < 16) wsum[lane] = w;
        }
        __syncthreads();
        if (wid > 0) incl3 += wsum[wid - 1];
        const unsigned excl3 = incl3 - s3;
        if (t < 128 && excl3 < k3 && k3 <= incl3) {
            bcast[2] = ((unsigned)sel1[ib] << SH1) | (sel2 << 7) | (unsigned)t;
        }
    }
    __syncthreads();
    const unsigned kth = bcast[2];

    // fix-up: rewrite only boundary-bin pixels
    float* m = out + 1 + (size_t)ib * NPIX;         // [A(0..7) | B(8..15)] contiguous
    for (unsigned j = t; j < n; j += 1024u) {
        const uint2 e = L[j];
        m[e.y] = (e.x >= kth) ? 1.0f : 0.0f;
    }
    if (ib == 0 && t == 0) out[0] = (float)(lossAcc[0] * (1.0 / 8388608.0));
}

extern "C" void kernel_launch(void* const* d_in, const int* in_sizes, int n_in,
                              void* d_out, int out_size, void* d_ws, size_t ws_size,
                              hipStream_t stream)
{
    const float* A = (const float*)d_in[0];
    const float* B = (const float*)d_in[1];
    const float* F = (const float*)d_in[2];
    const int* kptr = (const int*)d_in[3];
    float* out = (float*)d_out;

    if (ws_size < (size_t)WS_LIST_OFF + 16 * 8 * 1024) return;  // need hist area + some list space

    char* ws = (char*)d_ws;
    double* lossAcc        = (double*)(ws + WS_MISC_OFF);
    unsigned int* gCnt     = (unsigned int*)(ws + WS_MISC_OFF + 64);
    int* sel1              = (int*)(ws + WS_MISC_OFF + 128);
    int* resid1            = (int*)(ws + WS_MISC_OFF + 256);
    unsigned short* hist1p = (unsigned short*)(ws + WS_H1P_OFF);
    uint2* list            = (uint2*)(ws + WS_LIST_OFF);

    unsigned long long capll = (ws_size - WS_LIST_OFF) / (16ull * 8ull);
    unsigned cap = (capll > (unsigned long long)NPIX) ? (unsigned)NPIX : (unsigned)capll;

    hipMemsetAsync(ws, 0, WS_MISC_BYTES, stream);       // lossAcc + gCnt zeroed

    k_pass0    <<<dim3(NBATCH * SEGS), dim3(512), 0, stream>>>(A, B, F, hist1p, lossAcc);
    k_select1  <<<dim3(2 * NBATCH), dim3(1024), 0, stream>>>(hist1p, kptr, sel1, resid1);
    k_passB    <<<dim3(NBATCH * SEGS), dim3(512), 0, stream>>>(A, B, sel1, gCnt, list, cap, out);
    k_selectfix<<<dim3(2 * NBATCH), dim3(1024), 0, stream>>>(list, gCnt, cap, sel1, resid1, lossAcc, out);
}

// Round 2
// 322.450 us; speedup vs baseline: 1.3665x; 1.3665x over previous
//
#include <hip/hip_runtime.h>

#define IMG_H 1024
#define IMG_W 1024
#define NBATCH 8
#define NCH 3
#define NPIX (IMG_H * IMG_W)
#define NTOT (8388608LL)                // 8 * 1024 * 1024

#define BINS1 4096                      // level-1: bits >> 19
#define SH1 19

#define SEGS 64                         // 16-row bands per image (pass0 AND passB)
#define ROWS_PER_SEG 16

// ---- workspace layout (bytes) ----
#define WS_MISC_OFF   0                 // lossAcc @0 (8B), gCnt[16] @64, sel1 @128, resid1 @256
#define WS_H1R_OFF    4096
#define WS_H1R_BYTES  (2 * NBATCH * BINS1 * 4)          // 256 KB global u32 hist
#define WS_LOSSP_OFF  (WS_H1R_OFF + WS_H1R_BYTES)       // per-block loss partials
#define WS_LOSSP_BYTES (NBATCH * SEGS * 8)              // 4 KB
#define WS_LIST_OFF   (WS_LOSSP_OFF + WS_LOSSP_BYTES)

struct Row3f { float l, c, r; };

__device__ __forceinline__ Row3f load3(const float* __restrict__ img, int y, int x) {
    Row3f o;
    if ((unsigned)y >= (unsigned)IMG_H) { o.l = o.c = o.r = 0.0f; return o; }
    const float* row = img + (size_t)y * IMG_W;
    o.c = row[x];
    o.l = (x > 0)         ? row[x - 1] : 0.0f;
    o.r = (x < IMG_W - 1) ? row[x + 1] : 0.0f;
    return o;
}

// BIT-EXACT vs reference: f32, row-major sequential tap order (verified earlier session).
__device__ __forceinline__ float sobel_g(const Row3f& r0, const Row3f& r1, const Row3f& r2) {
    float gx = r0.r - r0.l;
    gx -= 2.0f * r1.l;
    gx += 2.0f * r1.r;
    gx -= r2.l;
    gx += r2.r;
    float gy = r0.l + 2.0f * r0.c;
    gy += r0.r;
    gy -= r2.l;
    gy -= 2.0f * r2.c;
    gy -= r2.r;
    return fabsf(gx) + fabsf(gy);
}

__device__ __forceinline__ unsigned wave_scan(unsigned s, int lane) {
    #pragma unroll
    for (int off = 1; off < 64; off <<= 1) {
        const unsigned v = __shfl_up(s, off);
        if (lane >= off) s += v;
    }
    return s;
}

// ---------------- pass 0: loss + level-1 hist, merged to global via skip-zero atomics ------
// 1024 thr, 64 KB LDS (2 replicated copies) -> 2 blocks/CU, 32 waves/CU (100% occupancy),
// same per-copy contention ratio as the round-0 kernel (8 waves/copy was 4/copy at 512thr:
// here 8 waves per copy but 2x the resident copies per CU -> equal serial streams per CU).
extern "C" __global__ __launch_bounds__(1024)
void k_pass0(const float* __restrict__ A, const float* __restrict__ B,
             const float* __restrict__ F,
             unsigned int* __restrict__ hist1r, double* __restrict__ lossPart)
{
    __shared__ unsigned int h[4 * BINS1];   // 64 KB: copy0[A|B], copy1[A|B]
    __shared__ double lsum[16];
    const int t = threadIdx.x;
    const int lane = t & 63;
    for (int i = t; i < 4 * BINS1; i += 1024) h[i] = 0u;
    __syncthreads();

    const int blk = blockIdx.x;             // 512 = 8 batches * 64 segs
    const int batch = blk >> 6;
    const int y0 = (blk & 63) * ROWS_PER_SEG;
    const int x = t;
    unsigned int* hc = h + (t >> 9) * (2 * BINS1);   // half-block replicated copy

    const float* a = A + (size_t)batch * NCH * NPIX;
    const float* b = B + (size_t)batch * NCH * NPIX;
    const float* f = F + (size_t)batch * NCH * NPIX;

    Row3f a0 = load3(a, y0 - 1, x), a1 = load3(a, y0, x), a2;
    Row3f b0 = load3(b, y0 - 1, x), b1 = load3(b, y0, x), b2;
    Row3f f0 = load3(f, y0 - 1, x), f1 = load3(f, y0, x), f2;

    double loss = 0.0;
    for (int i = 0; i < ROWS_PER_SEG; ++i) {
        const int y = y0 + i;
        a2 = load3(a, y + 1, x);
        b2 = load3(b, y + 1, x);
        f2 = load3(f, y + 1, x);
        const float gA = sobel_g(a0, a1, a2);
        const float gB = sobel_g(b0, b1, b2);
        const float gF = sobel_g(f0, f1, f2);
        atomicAdd(&hc[__float_as_uint(gA) >> SH1], 1u);
        atomicAdd(&hc[BINS1 + (__float_as_uint(gB) >> SH1)], 1u);
        loss += (double)fabsf(gF - fmaxf(gA, gB));
        a0 = a1; a1 = a2;
        b0 = b1; b1 = b2;
        f0 = f1; f1 = f2;
    }
    __syncthreads();

    // merge both copies and accumulate straight into the global hist (skip zero bins:
    // only a few hundred of the 4096 bins are touched per 16-row band)
    for (int i = t; i < 2 * BINS1; i += 1024) {
        const unsigned v = h[i] + h[2 * BINS1 + i];
        if (v) {
            unsigned int* dst = (i < BINS1)
                ? &hist1r[(size_t)batch * BINS1 + i]
                : &hist1r[(size_t)(NBATCH + batch) * BINS1 + (i - BINS1)];
            atomicAdd(dst, v);
        }
    }

    for (int off = 32; off > 0; off >>= 1) loss += __shfl_down(loss, off);
    if (lane == 0) lsum[t >> 6] = loss;
    __syncthreads();
    if (t == 0) {
        double s = 0.0;
        for (int i = 0; i < 16; ++i) s += lsum[i];
        lossPart[blk] = s;                  // plain store, no atomic, no zeroing needed
    }
}

// ---------------- select1: rank-select level-1 bin; also total loss + zero gCnt ------------
extern "C" __global__ __launch_bounds__(1024)
void k_select1(const unsigned int* __restrict__ hist1r, const double* __restrict__ lossPart,
               const int* __restrict__ kptr, int* __restrict__ sel1, int* __restrict__ resid1,
               double* __restrict__ lossAcc, unsigned int* __restrict__ gCnt)
{
    const int ib = blockIdx.x, t = threadIdx.x;     // 16 blocks: [A batches | B batches]
    const int lane = t & 63, wid = t >> 6;

    long long kl = (long long)kptr[0];
    if (kl < 1 || kl > (long long)NPIX) {           // defensive: scalar sent as f32?
        float kf = ((const float*)kptr)[0];
        kl = (long long)kf;
        if (kl < 1) kl = 1;
        if (kl > NPIX) kl = NPIX;
    }
    const unsigned k = (unsigned)kl;

    const uint4 c = ((const uint4*)(hist1r + (size_t)ib * BINS1))[t];   // bins 4t..4t+3
    const unsigned s = c.x + c.y + c.z + c.w;

    unsigned incl = wave_scan(s, lane);
    __shared__ unsigned wsum[16];
    __shared__ double dsum[16];
    if (lane == 63) wsum[wid] = incl;
    __syncthreads();
    if (wid == 0) {
        unsigned w = (lane < 16) ? wsum[lane] : 0u;
        w = wave_scan(w, lane);
        if (lane < 16) wsum[lane] = w;
    }
    __syncthreads();
    if (wid > 0) incl += wsum[wid - 1];

    const unsigned excl = incl - s;
    if (excl < k && k <= incl) {                    // unique winner thread
        unsigned cum = excl; int bin = t * 4;
        if (cum + c.x < k) { cum += c.x; ++bin;
          if (cum + c.y < k) { cum += c.y; ++bin;
            if (cum + c.z < k) { cum += c.z; ++bin; } } }
        sel1[ib] = bin;
        resid1[ib] = (int)(k - cum);
    }

    // block 0: reduce the 512 per-block loss partials (all other blocks idle through this)
    double v = 0.0;
    if (ib == 0 && t < NBATCH * SEGS) v = lossPart[t];
    for (int off = 32; off > 0; off >>= 1) v += __shfl_down(v, off);
    if (lane == 0) dsum[wid] = v;
    __syncthreads();
    if (ib == 0 && t == 0) {
        double sL = 0.0;
        for (int i = 0; i < 16; ++i) sL += dsum[i];
        lossAcc[0] = sL;
    }
    if (t == 0) gCnt[ib] = 0u;                      // zero counters for passB
}

// ---------------- pass B: masks + boundary-pixel candidate lists (block-staged) ------------
extern "C" __global__ __launch_bounds__(1024)
void k_passB(const float* __restrict__ A, const float* __restrict__ B,
             const int* __restrict__ sel1, unsigned int* __restrict__ gCnt,
             uint2* __restrict__ list, unsigned cap, float* __restrict__ out)
{
    const int t = threadIdx.x;
    const int blk = blockIdx.x;                     // 512 = 8 batches * 64 bands
    const int batch = blk >> 6;
    const int y0 = (blk & 63) * ROWS_PER_SEG;
    const int x = t;

    const float* a = A + (size_t)batch * NCH * NPIX;
    const float* b = B + (size_t)batch * NCH * NPIX;
    const unsigned sA = (unsigned)sel1[batch];
    const unsigned sB = (unsigned)sel1[NBATCH + batch];
    float* mA = out + 1 + (size_t)batch * NPIX;
    float* mB = out + 1 + (size_t)NTOT + (size_t)batch * NPIX;

    __shared__ uint2 bufA[2048], bufB[2048];        // 32 KB staging
    __shared__ unsigned cntA, cntB, baseA, baseB;
    if (t == 0) { cntA = 0u; cntB = 0u; }
    __syncthreads();

    Row3f a0 = load3(a, y0 - 1, x), a1 = load3(a, y0, x), a2;
    Row3f b0 = load3(b, y0 - 1, x), b1 = load3(b, y0, x), b2;
    for (int i = 0; i < ROWS_PER_SEG; ++i) {
        const int y = y0 + i;
        a2 = load3(a, y + 1, x);
        b2 = load3(b, y + 1, x);
        const unsigned uA = __float_as_uint(sobel_g(a0, a1, a2));
        const unsigned uB = __float_as_uint(sobel_g(b0, b1, b2));
        const unsigned binA = uA >> SH1, binB = uB >> SH1;
        const unsigned idx = (unsigned)y * IMG_W + (unsigned)x;
        mA[idx] = (binA > sA) ? 1.0f : 0.0f;        // boundary bin: provisional 0, fixed later
        mB[idx] = (binB > sB) ? 1.0f : 0.0f;
        if (binA == sA) { unsigned p = atomicAdd(&cntA, 1u); bufA[p] = make_uint2(uA, idx); }
        if (binB == sB) { unsigned p = atomicAdd(&cntB, 1u); bufB[p] = make_uint2(uB, idx); }
        a0 = a1; a1 = a2;
        b0 = b1; b1 = b2;

        __syncthreads();                            // appends visible, counters stable
        const bool last = (i == ROWS_PER_SEG - 1);
        const unsigned nA = cntA, nB = cntB;        // uniform
        const bool doA = (nA >= 1024u) || (last && nA > 0u);
        const bool doB = (nB >= 1024u) || (last && nB > 0u);
        if (doA || doB) {
            if (t == 0) {
                if (doA) baseA = atomicAdd(&gCnt[batch], nA);
                if (doB) baseB = atomicAdd(&gCnt[NBATCH + batch], nB);
            }
            __syncthreads();
            if (doA) {
                const unsigned bs = baseA;
                for (unsigned j = t; j < nA; j += 1024u) {
                    const unsigned d = bs + j;
                    if (d < cap) list[(size_t)batch * cap + d] = bufA[j];
                }
            }
            if (doB) {
                const unsigned bs = baseB;
                for (unsigned j = t; j < nB; j += 1024u) {
                    const unsigned d = bs + j;
                    if (d < cap) list[(size_t)(NBATCH + batch) * cap + d] = bufB[j];
                }
            }
            __syncthreads();
            if (t == 0) { if (doA) cntA = 0u; if (doB) cntB = 0u; }
        }
        __syncthreads();
    }
}

// ---------------- selectfix: 19-bit select within boundary bin + mask fix-up ----------------
extern "C" __global__ __launch_bounds__(1024)
void k_selectfix(const uint2* __restrict__ list, const unsigned int* __restrict__ gCnt,
                 unsigned cap, const int* __restrict__ sel1, const int* __restrict__ resid1,
                 const double* __restrict__ lossAcc, float* __restrict__ out)
{
    const int ib = blockIdx.x, t = threadIdx.x;     // 16 blocks: [A batches | B batches]
    const int lane = t & 63, wid = t >> 6;
    unsigned n = gCnt[ib]; if (n > cap) n = cap;
    const unsigned kk = (unsigned)resid1[ib];
    const uint2* L = list + (size_t)ib * cap;

    __shared__ unsigned h2[BINS1];                  // 16 KB, reused for h3
    __shared__ unsigned wsum[16];
    __shared__ unsigned bcast[4];
    if (t < 4) bcast[t] = 0u;
    for (int i = t; i < BINS1; i += 1024) h2[i] = 0u;
    __syncthreads();

    // level-2: hist of (bits>>7)&4095 (all entries share bits>>19 == sel1)
    for (unsigned j = t; j < n; j += 1024u) atomicAdd(&h2[(L[j].x >> 7) & 4095u], 1u);
    __syncthreads();

    const unsigned c0 = h2[4 * t], c1 = h2[4 * t + 1], c2 = h2[4 * t + 2], c3 = h2[4 * t + 3];
    const unsigned s = c0 + c1 + c2 + c3;
    unsigned incl = wave_scan(s, lane);
    if (lane == 63) wsum[wid] = incl;
    __syncthreads();
    if (wid == 0) {
        unsigned w = (lane < 16) ? wsum[lane] : 0u;
        w = wave_scan(w, lane);
        if (lane < 16) wsum[lane] = w;
    }
    __syncthreads();
    if (wid > 0) incl += wsum[wid - 1];
    {
        const unsigned excl = incl - s;
        if (excl < kk && kk <= incl) {
            unsigned cum = excl; unsigned bin = 4u * t;
            if (cum + c0 < kk) { cum += c0; ++bin;
              if (cum + c1 < kk) { cum += c1; ++bin;
                if (cum + c2 < kk) { cum += c2; ++bin; } } }
            bcast[0] = bin;
            bcast[1] = kk - cum;
        }
    }
    __syncthreads();
    const unsigned sel2 = bcast[0], k3 = bcast[1];

    // level-3: hist of bits&127 among entries matching sel2
    if (t < 128) h2[t] = 0u;
    __syncthreads();
    for (unsigned j = t; j < n; j += 1024u) {
        const unsigned bbits = L[j].x;
        if (((bbits >> 7) & 4095u) == sel2) atomicAdd(&h2[bbits & 127u], 1u);
    }
    __syncthreads();
    {
        const unsigned s3 = (t < 128) ? h2[t] : 0u;
        unsigned incl3 = wave_scan(s3, lane);
        if (lane == 63) wsum[wid] = incl3;
        __syncthreads();
        if (wid == 0) {
            unsigned w = (lane < 16) ? wsum[lane] : 0u;
            w = wave_scan(w, lane);
            if (lane < 16) wsum[lane] = w;
        }
        __syncthreads();
        if (wid > 0) incl3 += wsum[wid - 1];
        const unsigned excl3 = incl3 - s3;
        if (t < 128 && excl3 < k3 && k3 <= incl3) {
            bcast[2] = ((unsigned)sel1[ib] << SH1) | (sel2 << 7) | (unsigned)t;
        }
    }
    __syncthreads();
    const unsigned kth = bcast[2];

    // fix-up: rewrite only boundary-bin pixels
    float* m = out + 1 + (size_t)ib * NPIX;         // [A(0..7) | B(8..15)] contiguous
    for (unsigned j = t; j < n; j += 1024u) {
        const uint2 e = L[j];
        m[e.y] = (e.x >= kth) ? 1.0f : 0.0f;
    }
    if (ib == 0 && t == 0) out[0] = (float)(lossAcc[0] * (1.0 / 8388608.0));
}

extern "C" void kernel_launch(void* const* d_in, const int* in_sizes, int n_in,
                              void* d_out, int out_size, void* d_ws, size_t ws_size,
                              hipStream_t stream)
{
    const float* A = (const float*)d_in[0];
    const float* B = (const float*)d_in[1];
    const float* F = (const float*)d_in[2];
    const int* kptr = (const int*)d_in[3];
    float* out = (float*)d_out;

    if (ws_size < (size_t)WS_LIST_OFF + 16 * 8 * 1024) return;

    char* ws = (char*)d_ws;
    double* lossAcc        = (double*)(ws + WS_MISC_OFF);
    unsigned int* gCnt     = (unsigned int*)(ws + WS_MISC_OFF + 64);
    int* sel1              = (int*)(ws + WS_MISC_OFF + 128);
    int* resid1            = (int*)(ws + WS_MISC_OFF + 256);
    unsigned int* hist1r   = (unsigned int*)(ws + WS_H1R_OFF);
    double* lossPart       = (double*)(ws + WS_LOSSP_OFF);
    uint2* list            = (uint2*)(ws + WS_LIST_OFF);

    unsigned long long capll = (ws_size - WS_LIST_OFF) / (16ull * 8ull);
    unsigned cap = (capll > (unsigned long long)NPIX) ? (unsigned)NPIX : (unsigned)capll;

    hipMemsetAsync(ws + WS_H1R_OFF, 0, WS_H1R_BYTES, stream);   // only the global hist needs zeroing

    k_pass0    <<<dim3(NBATCH * SEGS), dim3(1024), 0, stream>>>(A, B, F, hist1r, lossPart);
    k_select1  <<<dim3(2 * NBATCH), dim3(1024), 0, stream>>>(hist1r, lossPart, kptr, sel1, resid1, lossAcc, gCnt);
    k_passB    <<<dim3(NBATCH * SEGS), dim3(1024), 0, stream>>>(A, B, sel1, gCnt, list, cap, out);
    k_selectfix<<<dim3(2 * NBATCH), dim3(1024), 0, stream>>>(list, gCnt, cap, sel1, resid1, lossAcc, out);
}